// Round 1
// baseline (2299.628 us; speedup 1.0000x reference)
//
#include <hip/hip_runtime.h>
#include <hip/hip_bf16.h>
#include <cstdint>

typedef __attribute__((ext_vector_type(8))) short short8;
typedef __attribute__((ext_vector_type(4))) float f32x4;

#define B_  2
#define S_  2048
#define D_  1024
#define H_  16
#define HD  64

static __device__ __forceinline__ float bf2f(unsigned int u16) {
    union { unsigned int i; float f; } v; v.i = u16 << 16; return v.f;
}
static __device__ __forceinline__ unsigned short f2bf(float f) {
    union { float f; unsigned int i; } v; v.f = f;
    unsigned int r = v.i + 0x7FFFu + ((v.i >> 16) & 1u);
    return (unsigned short)(r >> 16);
}

// ---------------- fp32 -> bf16 conversion (vectorized x4) ----------------
__global__ void cvt_f32_bf16(const float* __restrict__ src,
                             unsigned short* __restrict__ dst, int n4) {
    int i = blockIdx.x * 256 + threadIdx.x;
    if (i >= n4) return;
    float4 f = ((const float4*)src)[i];
    uint2 o;
    o.x = (unsigned int)f2bf(f.x) | ((unsigned int)f2bf(f.y) << 16);
    o.y = (unsigned int)f2bf(f.z) | ((unsigned int)f2bf(f.w) << 16);
    ((uint2*)dst)[i] = o;
}

// ---------------- fused QKV GEMM: C = x @ W^T, one wave per 64x64 tile ----
// A (xbf): [4096,1024] bf16 row-major. W: [1024,1024] bf16 row-major (B^T form).
// Output scattered to [B,H,S,hd] bf16.
__global__ __launch_bounds__(64) void qkv_gemm(
    const unsigned short* __restrict__ xbf,
    const unsigned short* __restrict__ wq,
    const unsigned short* __restrict__ wk,
    const unsigned short* __restrict__ wv,
    unsigned short* __restrict__ qb,
    unsigned short* __restrict__ kb,
    unsigned short* __restrict__ vb)
{
    const int m0 = blockIdx.x * 64;
    const int nc = blockIdx.y * 64;          // 0..3071
    const int sel = nc >> 10;                // 0=q 1=k 2=v
    const int n0 = nc & 1023;
    const unsigned short* __restrict__ W = sel == 0 ? wq : (sel == 1 ? wk : wv);
    unsigned short* __restrict__ Out = sel == 0 ? qb : (sel == 1 ? kb : vb);

    const int lane = threadIdx.x;
    const int row  = lane & 15;
    const int quad = lane >> 4;

    f32x4 acc[4][4] = {};
    const unsigned short* aBase = xbf + (size_t)(m0 + row) * D_ + quad * 8;
    const unsigned short* bBase = W   + (size_t)(n0 + row) * D_ + quad * 8;

    for (int k0 = 0; k0 < D_; k0 += 32) {
        short8 a[4], b[4];
#pragma unroll
        for (int i = 0; i < 4; i++) {
            a[i] = *(const short8*)(aBase + i * 16 * D_ + k0);
            b[i] = *(const short8*)(bBase + i * 16 * D_ + k0);
        }
#pragma unroll
        for (int i = 0; i < 4; i++)
#pragma unroll
            for (int j = 0; j < 4; j++)
                acc[i][j] = __builtin_amdgcn_mfma_f32_16x16x32_bf16(a[i], b[j], acc[i][j], 0, 0, 0);
    }

#pragma unroll
    for (int i = 0; i < 4; i++) {
#pragma unroll
        for (int r = 0; r < 4; r++) {
            int m = m0 + i * 16 + quad * 4 + r;
            int bb = m >> 11;            // /2048
            int s  = m & 2047;
#pragma unroll
            for (int j = 0; j < 4; j++) {
                int col = n0 + j * 16 + row;
                int h = col >> 6, d = col & 63;
                Out[(((size_t)(bb * H_ + h) * S_) + s) * HD + d] = f2bf(acc[i][j][r]);
            }
        }
    }
}

// ---------------- output GEMM: out = attn_cat @ Wo^T (fp32 out) ----------
__global__ __launch_bounds__(64) void out_gemm(
    const unsigned short* __restrict__ A,    // attn_cat bf16 [4096,1024]
    const unsigned short* __restrict__ Bt,   // Wo bf16 [1024,1024]
    float* __restrict__ C)                   // [4096,1024] fp32
{
    const int m0 = blockIdx.x * 64;
    const int n0 = blockIdx.y * 64;
    const int lane = threadIdx.x;
    const int row  = lane & 15;
    const int quad = lane >> 4;

    f32x4 acc[4][4] = {};
    const unsigned short* aBase = A  + (size_t)(m0 + row) * D_ + quad * 8;
    const unsigned short* bBase = Bt + (size_t)(n0 + row) * D_ + quad * 8;

    for (int k0 = 0; k0 < D_; k0 += 32) {
        short8 a[4], b[4];
#pragma unroll
        for (int i = 0; i < 4; i++) {
            a[i] = *(const short8*)(aBase + i * 16 * D_ + k0);
            b[i] = *(const short8*)(bBase + i * 16 * D_ + k0);
        }
#pragma unroll
        for (int i = 0; i < 4; i++)
#pragma unroll
            for (int j = 0; j < 4; j++)
                acc[i][j] = __builtin_amdgcn_mfma_f32_16x16x32_bf16(a[i], b[j], acc[i][j], 0, 0, 0);
    }

#pragma unroll
    for (int i = 0; i < 4; i++)
#pragma unroll
        for (int r = 0; r < 4; r++) {
            int m = m0 + i * 16 + quad * 4 + r;
#pragma unroll
            for (int j = 0; j < 4; j++)
                C[(size_t)m * D_ + n0 + j * 16 + row] = acc[i][j][r];
        }
}

// ---------------- RoPE on Q and K in [B,H,S,hd] bf16 ---------------------
__global__ void rope_qk(unsigned short* __restrict__ qb,
                        unsigned short* __restrict__ kb,
                        const float* __restrict__ fcos,
                        const float* __restrict__ fsin)
{
    int idx = blockIdx.x * 256 + threadIdx.x;        // 2M pairs
    int t  = idx & 31;
    int s  = (idx >> 5) & (S_ - 1);
    int bh = idx >> 16;                              // S_*32 == 65536
    float c  = fcos[s * 32 + t];
    float si = fsin[s * 32 + t];
    size_t off = ((size_t)bh * S_ + s) * HD + 2 * t;

    unsigned int* qp = (unsigned int*)(qb + off);
    unsigned int u = *qp;
    float r = bf2f(u & 0xffffu), im = bf2f(u >> 16);
    float a  = r * c - im * si;
    float b2 = im * c + r * si;
    *qp = (unsigned int)f2bf(a) | ((unsigned int)f2bf(b2) << 16);

    unsigned int* kp = (unsigned int*)(kb + off);
    u = *kp;
    r = bf2f(u & 0xffffu); im = bf2f(u >> 16);
    a  = r * c - im * si;
    b2 = im * c + r * si;
    *kp = (unsigned int)f2bf(a) | ((unsigned int)f2bf(b2) << 16);
}

// ---------------- causal flash attention (VALU, thread-per-row) ----------
// grid: (32 bh, 8 qtile), block 256. Each thread owns one query row.
__global__ __launch_bounds__(256) void flash_attn(
    const unsigned short* __restrict__ qb,
    const unsigned short* __restrict__ kb,
    const unsigned short* __restrict__ vb,
    unsigned short* __restrict__ attnc)
{
    __shared__ float Ks[64][64];
    __shared__ float Vs[64][64];

    const int bh  = blockIdx.x;       // 0..31
    const int qt  = blockIdx.y;       // 0..7
    const int tid = threadIdx.x;
    const int r   = qt * 256 + tid;   // query row 0..2047
    const int b   = bh >> 4, h = bh & 15;

    float qv[64];
    const unsigned short* qptr = qb + ((size_t)bh * S_ + r) * HD;
#pragma unroll
    for (int c8 = 0; c8 < 8; c8++) {
        uint4 u = *(const uint4*)(qptr + c8 * 8);
        qv[c8 * 8 + 0] = bf2f(u.x & 0xffffu); qv[c8 * 8 + 1] = bf2f(u.x >> 16);
        qv[c8 * 8 + 2] = bf2f(u.y & 0xffffu); qv[c8 * 8 + 3] = bf2f(u.y >> 16);
        qv[c8 * 8 + 4] = bf2f(u.z & 0xffffu); qv[c8 * 8 + 5] = bf2f(u.z >> 16);
        qv[c8 * 8 + 6] = bf2f(u.w & 0xffffu); qv[c8 * 8 + 7] = bf2f(u.w >> 16);
    }

    float m = -INFINITY, l = 0.0f;
    float o[64];
#pragma unroll
    for (int d = 0; d < 64; d++) o[d] = 0.0f;

    const int ntiles = qt * 4 + 4;
    for (int jt = 0; jt < ntiles; jt++) {
        const int j0 = jt * 64;
        {   // stage 64x64 K and V tiles, bf16 -> fp32
            int jj = tid >> 2;
            int dc = (tid & 3) << 4;
            const unsigned short* kp = kb + ((size_t)bh * S_ + j0 + jj) * HD + dc;
            const unsigned short* vp = vb + ((size_t)bh * S_ + j0 + jj) * HD + dc;
#pragma unroll
            for (int q8 = 0; q8 < 2; q8++) {
                uint4 u = *(const uint4*)(kp + q8 * 8);
                float4* dk = (float4*)&Ks[jj][dc + q8 * 8];
                dk[0] = make_float4(bf2f(u.x & 0xffffu), bf2f(u.x >> 16),
                                    bf2f(u.y & 0xffffu), bf2f(u.y >> 16));
                dk[1] = make_float4(bf2f(u.z & 0xffffu), bf2f(u.z >> 16),
                                    bf2f(u.w & 0xffffu), bf2f(u.w >> 16));
                uint4 w = *(const uint4*)(vp + q8 * 8);
                float4* dv = (float4*)&Vs[jj][dc + q8 * 8];
                dv[0] = make_float4(bf2f(w.x & 0xffffu), bf2f(w.x >> 16),
                                    bf2f(w.y & 0xffffu), bf2f(w.y >> 16));
                dv[1] = make_float4(bf2f(w.z & 0xffffu), bf2f(w.z >> 16),
                                    bf2f(w.w & 0xffffu), bf2f(w.w >> 16));
            }
        }
        __syncthreads();

        int e = r - j0 + 1;
        if (e > 64) e = 64;
        for (int jj = 0; jj < e; jj++) {
            float s = 0.0f;
            const float4* kk = (const float4*)Ks[jj];
#pragma unroll
            for (int d4 = 0; d4 < 16; d4++) {
                float4 kv = kk[d4];
                s += qv[d4 * 4 + 0] * kv.x + qv[d4 * 4 + 1] * kv.y
                   + qv[d4 * 4 + 2] * kv.z + qv[d4 * 4 + 3] * kv.w;
            }
            s *= 0.125f;
            float mn = fmaxf(m, s);
            float p  = __expf(s - mn);
            float cc = __expf(m - mn);
            l = l * cc + p;
            m = mn;
            const float4* vv = (const float4*)Vs[jj];
#pragma unroll
            for (int d4 = 0; d4 < 16; d4++) {
                float4 v4 = vv[d4];
                o[d4 * 4 + 0] = o[d4 * 4 + 0] * cc + p * v4.x;
                o[d4 * 4 + 1] = o[d4 * 4 + 1] * cc + p * v4.y;
                o[d4 * 4 + 2] = o[d4 * 4 + 2] * cc + p * v4.z;
                o[d4 * 4 + 3] = o[d4 * 4 + 3] * cc + p * v4.w;
            }
        }
        __syncthreads();
    }

    float inv = 1.0f / l;
    unsigned short* op = attnc + (((size_t)b * S_ + r) * H_ + h) * HD;
#pragma unroll
    for (int d2 = 0; d2 < 32; d2++) {
        unsigned int u = (unsigned int)f2bf(o[2 * d2] * inv)
                       | ((unsigned int)f2bf(o[2 * d2 + 1] * inv) << 16);
        ((unsigned int*)op)[d2] = u;
    }
}

// ---------------- launch ----------------
extern "C" void kernel_launch(void* const* d_in, const int* in_sizes, int n_in,
                              void* d_out, int out_size, void* d_ws, size_t ws_size,
                              hipStream_t stream) {
    const float* x    = (const float*)d_in[0];
    const float* fcos = (const float*)d_in[1];
    const float* fsin = (const float*)d_in[2];
    const float* Wq   = (const float*)d_in[3];
    const float* Wk   = (const float*)d_in[4];
    const float* Wv   = (const float*)d_in[5];
    const float* Wo   = (const float*)d_in[6];
    float* out = (float*)d_out;

    unsigned short* ws = (unsigned short*)d_ws;
    unsigned short* xbf = ws;                      // 4M elems
    unsigned short* wqb = xbf + 4096 * 1024;       // 1M
    unsigned short* wkb = wqb + 1024 * 1024;
    unsigned short* wvb = wkb + 1024 * 1024;
    unsigned short* wob = wvb + 1024 * 1024;
    unsigned short* qb  = wob + 1024 * 1024;       // 4M each
    unsigned short* kb  = qb + 4096 * 1024;
    unsigned short* vb  = kb + 4096 * 1024;
    unsigned short* attnc = vb + 4096 * 1024;      // 4M
    // total 24M ushorts = 48 MB

    // 1. convert inputs to bf16
    cvt_f32_bf16<<<4096, 256, 0, stream>>>(x,  xbf, 4096 * 1024 / 4);
    cvt_f32_bf16<<<1024, 256, 0, stream>>>(Wq, wqb, 1024 * 1024 / 4);
    cvt_f32_bf16<<<1024, 256, 0, stream>>>(Wk, wkb, 1024 * 1024 / 4);
    cvt_f32_bf16<<<1024, 256, 0, stream>>>(Wv, wvb, 1024 * 1024 / 4);
    cvt_f32_bf16<<<1024, 256, 0, stream>>>(Wo, wob, 1024 * 1024 / 4);

    // 2. fused QKV projection
    qkv_gemm<<<dim3(64, 48), 64, 0, stream>>>(xbf, wqb, wkb, wvb, qb, kb, vb);

    // 3. RoPE on Q, K
    rope_qk<<<8192, 256, 0, stream>>>(qb, kb, fcos, fsin);

    // 4. causal flash attention
    flash_attn<<<dim3(32, 8), 256, 0, stream>>>(qb, kb, vb, attnc);

    // 5. output projection
    out_gemm<<<dim3(64, 16), 64, 0, stream>>>(attnc, wob, out);
}

// Round 2
// 321.071 us; speedup vs baseline: 7.1624x; 7.1624x over previous
//
#include <hip/hip_runtime.h>
#include <hip/hip_bf16.h>
#include <cstdint>

typedef __attribute__((ext_vector_type(8))) short short8;
typedef __attribute__((ext_vector_type(4))) float f32x4;

#define B_  2
#define S_  2048
#define D_  1024
#define H_  16
#define HD  64

static __device__ __forceinline__ float bf2f(unsigned int u16) {
    union { unsigned int i; float f; } v; v.i = u16 << 16; return v.f;
}
static __device__ __forceinline__ unsigned short f2bf(float f) {
    union { float f; unsigned int i; } v; v.f = f;
    unsigned int r = v.i + 0x7FFFu + ((v.i >> 16) & 1u);
    return (unsigned short)(r >> 16);
}

// ---------------- fp32 -> bf16 conversion (vectorized x4) ----------------
__global__ void cvt_f32_bf16(const float* __restrict__ src,
                             unsigned short* __restrict__ dst, int n4) {
    int i = blockIdx.x * 256 + threadIdx.x;
    if (i >= n4) return;
    float4 f = ((const float4*)src)[i];
    uint2 o;
    o.x = (unsigned int)f2bf(f.x) | ((unsigned int)f2bf(f.y) << 16);
    o.y = (unsigned int)f2bf(f.z) | ((unsigned int)f2bf(f.w) << 16);
    ((uint2*)dst)[i] = o;
}

// ---------------- fused QKV GEMM: C = x @ W^T, one wave per 64x64 tile ----
__global__ __launch_bounds__(64) void qkv_gemm(
    const unsigned short* __restrict__ xbf,
    const unsigned short* __restrict__ wq,
    const unsigned short* __restrict__ wk,
    const unsigned short* __restrict__ wv,
    unsigned short* __restrict__ qb,
    unsigned short* __restrict__ kb,
    unsigned short* __restrict__ vb)
{
    const int m0 = blockIdx.x * 64;
    const int nc = blockIdx.y * 64;          // 0..3071
    const int sel = nc >> 10;                // 0=q 1=k 2=v
    const int n0 = nc & 1023;
    const unsigned short* __restrict__ W = sel == 0 ? wq : (sel == 1 ? wk : wv);
    unsigned short* __restrict__ Out = sel == 0 ? qb : (sel == 1 ? kb : vb);

    const int lane = threadIdx.x;
    const int row  = lane & 15;
    const int quad = lane >> 4;

    f32x4 acc[4][4] = {};
    const unsigned short* aBase = xbf + (size_t)(m0 + row) * D_ + quad * 8;
    const unsigned short* bBase = W   + (size_t)(n0 + row) * D_ + quad * 8;

    for (int k0 = 0; k0 < D_; k0 += 32) {
        short8 a[4], b[4];
#pragma unroll
        for (int i = 0; i < 4; i++) {
            a[i] = *(const short8*)(aBase + i * 16 * D_ + k0);
            b[i] = *(const short8*)(bBase + i * 16 * D_ + k0);
        }
#pragma unroll
        for (int i = 0; i < 4; i++)
#pragma unroll
            for (int j = 0; j < 4; j++)
                acc[i][j] = __builtin_amdgcn_mfma_f32_16x16x32_bf16(a[i], b[j], acc[i][j], 0, 0, 0);
    }

#pragma unroll
    for (int i = 0; i < 4; i++) {
#pragma unroll
        for (int r = 0; r < 4; r++) {
            int m = m0 + i * 16 + quad * 4 + r;
            int bb = m >> 11;            // /2048
            int s  = m & 2047;
#pragma unroll
            for (int j = 0; j < 4; j++) {
                int col = n0 + j * 16 + row;
                int h = col >> 6, d = col & 63;
                Out[(((size_t)(bb * H_ + h) * S_) + s) * HD + d] = f2bf(acc[i][j][r]);
            }
        }
    }
}

// ---------------- output GEMM: out = attn_cat @ Wo^T (fp32 out) ----------
__global__ __launch_bounds__(64) void out_gemm(
    const unsigned short* __restrict__ A,    // attn_cat bf16 [4096,1024]
    const unsigned short* __restrict__ Bt,   // Wo bf16 [1024,1024]
    float* __restrict__ C)                   // [4096,1024] fp32
{
    const int m0 = blockIdx.x * 64;
    const int n0 = blockIdx.y * 64;
    const int lane = threadIdx.x;
    const int row  = lane & 15;
    const int quad = lane >> 4;

    f32x4 acc[4][4] = {};
    const unsigned short* aBase = A  + (size_t)(m0 + row) * D_ + quad * 8;
    const unsigned short* bBase = Bt + (size_t)(n0 + row) * D_ + quad * 8;

    for (int k0 = 0; k0 < D_; k0 += 32) {
        short8 a[4], b[4];
#pragma unroll
        for (int i = 0; i < 4; i++) {
            a[i] = *(const short8*)(aBase + i * 16 * D_ + k0);
            b[i] = *(const short8*)(bBase + i * 16 * D_ + k0);
        }
#pragma unroll
        for (int i = 0; i < 4; i++)
#pragma unroll
            for (int j = 0; j < 4; j++)
                acc[i][j] = __builtin_amdgcn_mfma_f32_16x16x32_bf16(a[i], b[j], acc[i][j], 0, 0, 0);
    }

#pragma unroll
    for (int i = 0; i < 4; i++)
#pragma unroll
        for (int r = 0; r < 4; r++) {
            int m = m0 + i * 16 + quad * 4 + r;
#pragma unroll
            for (int j = 0; j < 4; j++)
                C[(size_t)m * D_ + n0 + j * 16 + row] = acc[i][j][r];
        }
}

// ---------------- RoPE on Q and K in [B,H,S,hd] bf16 ---------------------
__global__ void rope_qk(unsigned short* __restrict__ qb,
                        unsigned short* __restrict__ kb,
                        const float* __restrict__ fcos,
                        const float* __restrict__ fsin)
{
    int idx = blockIdx.x * 256 + threadIdx.x;        // 2M pairs
    int t  = idx & 31;
    int s  = (idx >> 5) & (S_ - 1);
    int bh = idx >> 16;                              // S_*32 == 65536
    float c  = fcos[s * 32 + t];
    float si = fsin[s * 32 + t];
    size_t off = ((size_t)bh * S_ + s) * HD + 2 * t;

    unsigned int* qp = (unsigned int*)(qb + off);
    unsigned int u = *qp;
    float r = bf2f(u & 0xffffu), im = bf2f(u >> 16);
    float a  = r * c - im * si;
    float b2 = im * c + r * si;
    *qp = (unsigned int)f2bf(a) | ((unsigned int)f2bf(b2) << 16);

    unsigned int* kp = (unsigned int*)(kb + off);
    u = *kp;
    r = bf2f(u & 0xffffu); im = bf2f(u >> 16);
    a  = r * c - im * si;
    b2 = im * c + r * si;
    *kp = (unsigned int)f2bf(a) | ((unsigned int)f2bf(b2) << 16);
}

// ---------------- causal flash attention, MFMA version -------------------
// grid: (32 bh, 32 qtile), block 256 (4 waves). Each wave owns 16 q rows.
// S^T = K·Q^T via mfma_16x16x32 (C layout: q=lane&15, key=quad*4+reg).
// Softmax stats per q need only in-lane reduce + shfl_xor(16,32).
// P -> A-operand layout via within-wave LDS round-trip; PV via mfma_16x16x32
// against V^T staged in LDS.
__global__ __launch_bounds__(256) void flash_attn_mfma(
    const unsigned short* __restrict__ qb,
    const unsigned short* __restrict__ kb,
    const unsigned short* __restrict__ vb,
    unsigned short* __restrict__ attnc)
{
    __shared__ unsigned short Ks[64][80];      // K tile, natural, padded for b128
    __shared__ unsigned short Vt[64][72];      // V^T tile (row=d, col=j), padded
    __shared__ unsigned short Pls[4][16][72];  // per-wave P round-trip buffer

    const int bh   = blockIdx.x;      // 0..31
    const int qt   = blockIdx.y;      // 0..31
    const int b    = bh >> 4, h = bh & 15;
    const int tid  = threadIdx.x;
    const int w    = tid >> 6;        // wave 0..3
    const int lane = tid & 63;
    const int l15  = lane & 15;
    const int quad = lane >> 4;

    const size_t bhS = (size_t)bh * S_;

    // Q fragments for this wave's 16 rows (B-operand: outer=q=l15, k=quad*8+j)
    short8 qfrag[2];
    {
        const unsigned short* qp = qb + (bhS + qt * 64 + w * 16 + l15) * HD + quad * 8;
        qfrag[0] = *(const short8*)(qp);
        qfrag[1] = *(const short8*)(qp + 32);
    }

    f32x4 O[4] = {};          // O[dt]: value at (q=quad*4+r, d=dt*16+l15)
    float mrow = -INFINITY;   // row stats for q = l15
    float lrow = 0.0f;
    const float sc = 0.125f * 1.44269504f;   // 1/sqrt(64) * log2(e)

    for (int jt = 0; jt <= qt; jt++) {
        const int j0 = jt * 64;
        // ---- stage K tile (natural) and V^T tile ----
        {
            int jj = tid >> 2, cg = tid & 3;
            const unsigned short* kp = kb + (bhS + j0 + jj) * HD + cg * 16;
            uint4 k0 = *(const uint4*)kp;
            uint4 k1 = *(const uint4*)(kp + 8);
            *(uint4*)&Ks[jj][cg * 16]     = k0;
            *(uint4*)&Ks[jj][cg * 16 + 8] = k1;

            int p = tid >> 3, dg = tid & 7;
            const unsigned short* vp = vb + (bhS + j0 + 2 * p) * HD + dg * 8;
            uint4 v0 = *(const uint4*)vp;
            uint4 v1 = *(const uint4*)(vp + HD);
            const unsigned short* va = (const unsigned short*)&v0;
            const unsigned short* vc = (const unsigned short*)&v1;
#pragma unroll
            for (int i = 0; i < 8; i++) {
                unsigned int val = (unsigned int)va[i] | ((unsigned int)vc[i] << 16);
                *(unsigned int*)&Vt[dg * 8 + i][2 * p] = val;
            }
        }
        __syncthreads();

        const bool diag  = (jt == qt);
        const int  nsub  = diag ? (w + 1) : 4;       // 16-key subtiles to compute
        const int  kgmax = (nsub + 1) >> 1;          // 32-key groups for PV

        // ---- S^T = K·Q^T ----
        f32x4 Sacc[4];
        float tmax = -INFINITY;
        for (int sub = 0; sub < nsub; sub++) {
            f32x4 s = {};
#pragma unroll
            for (int kh = 0; kh < 2; kh++) {
                short8 kf = *(const short8*)&Ks[sub * 16 + l15][kh * 32 + quad * 8];
                s = __builtin_amdgcn_mfma_f32_16x16x32_bf16(kf, qfrag[kh], s, 0, 0, 0);
            }
#pragma unroll
            for (int r = 0; r < 4; r++) {
                float v = s[r] * sc;
                if (diag && (sub * 16 + quad * 4 + r > w * 16 + l15)) v = -INFINITY;
                s[r] = v;
                tmax = fmaxf(tmax, v);
            }
            Sacc[sub] = s;
        }
        tmax = fmaxf(tmax, __shfl_xor(tmax, 16, 64));
        tmax = fmaxf(tmax, __shfl_xor(tmax, 32, 64));

        float mnew = fmaxf(mrow, tmax);
        float ccr  = __builtin_amdgcn_exp2f(mrow - mnew);   // 0 on first tile

        float psum = 0.0f;
        for (int sub = 0; sub < nsub; sub++) {
            f32x4 s = Sacc[sub];
            float p0 = __builtin_amdgcn_exp2f(s[0] - mnew);
            float p1 = __builtin_amdgcn_exp2f(s[1] - mnew);
            float p2 = __builtin_amdgcn_exp2f(s[2] - mnew);
            float p3 = __builtin_amdgcn_exp2f(s[3] - mnew);
            psum += (p0 + p1) + (p2 + p3);
            uint2 pk;
            pk.x = (unsigned int)f2bf(p0) | ((unsigned int)f2bf(p1) << 16);
            pk.y = (unsigned int)f2bf(p2) | ((unsigned int)f2bf(p3) << 16);
            *(uint2*)&Pls[w][l15][sub * 16 + quad * 4] = pk;
        }
        if (diag) {
            for (int sub = nsub; sub < 2 * kgmax; sub++) {
                uint2 z; z.x = 0u; z.y = 0u;
                *(uint2*)&Pls[w][l15][sub * 16 + quad * 4] = z;
            }
        }
        psum += __shfl_xor(psum, 16, 64);
        psum += __shfl_xor(psum, 32, 64);
        lrow = lrow * ccr + psum;
        mrow = mnew;

        // ---- O rescale (stats live at q=l15; O rows are q=quad*4+r) ----
#pragma unroll
        for (int r = 0; r < 4; r++) {
            float ccq = __shfl(ccr, quad * 4 + r, 64);
#pragma unroll
            for (int dt = 0; dt < 4; dt++) O[dt][r] *= ccq;
        }

        // ---- PV: O += P · V  (P via LDS round-trip, V^T in LDS) ----
        for (int kg = 0; kg < kgmax; kg++) {
            short8 pf = *(const short8*)&Pls[w][l15][kg * 32 + quad * 8];
#pragma unroll
            for (int dt = 0; dt < 4; dt++) {
                short8 vf = *(const short8*)&Vt[dt * 16 + l15][kg * 32 + quad * 8];
                O[dt] = __builtin_amdgcn_mfma_f32_16x16x32_bf16(pf, vf, O[dt], 0, 0, 0);
            }
        }
        __syncthreads();
    }

    // ---- epilogue: divide by l, store bf16 to attn_cat [B,S,H*hd] ----
    float inv = 1.0f / lrow;    // for q = l15
#pragma unroll
    for (int r = 0; r < 4; r++) {
        float invq = __shfl(inv, quad * 4 + r, 64);
        int qabs = qt * 64 + w * 16 + quad * 4 + r;
        unsigned short* op = attnc + (((size_t)b * S_ + qabs) * H_ + h) * HD + l15;
#pragma unroll
        for (int dt = 0; dt < 4; dt++)
            op[dt * 16] = f2bf(O[dt][r] * invq);
    }
}

// ---------------- launch ----------------
extern "C" void kernel_launch(void* const* d_in, const int* in_sizes, int n_in,
                              void* d_out, int out_size, void* d_ws, size_t ws_size,
                              hipStream_t stream) {
    const float* x    = (const float*)d_in[0];
    const float* fcos = (const float*)d_in[1];
    const float* fsin = (const float*)d_in[2];
    const float* Wq   = (const float*)d_in[3];
    const float* Wk   = (const float*)d_in[4];
    const float* Wv   = (const float*)d_in[5];
    const float* Wo   = (const float*)d_in[6];
    float* out = (float*)d_out;

    unsigned short* ws = (unsigned short*)d_ws;
    unsigned short* xbf = ws;                      // 4M elems
    unsigned short* wqb = xbf + 4096 * 1024;       // 1M
    unsigned short* wkb = wqb + 1024 * 1024;
    unsigned short* wvb = wkb + 1024 * 1024;
    unsigned short* wob = wvb + 1024 * 1024;
    unsigned short* qb  = wob + 1024 * 1024;       // 4M each
    unsigned short* kb  = qb + 4096 * 1024;
    unsigned short* vb  = kb + 4096 * 1024;
    unsigned short* attnc = vb + 4096 * 1024;      // 4M
    // total 24M ushorts = 48 MB

    // 1. convert inputs to bf16
    cvt_f32_bf16<<<4096, 256, 0, stream>>>(x,  xbf, 4096 * 1024 / 4);
    cvt_f32_bf16<<<1024, 256, 0, stream>>>(Wq, wqb, 1024 * 1024 / 4);
    cvt_f32_bf16<<<1024, 256, 0, stream>>>(Wk, wkb, 1024 * 1024 / 4);
    cvt_f32_bf16<<<1024, 256, 0, stream>>>(Wv, wvb, 1024 * 1024 / 4);
    cvt_f32_bf16<<<1024, 256, 0, stream>>>(Wo, wob, 1024 * 1024 / 4);

    // 2. fused QKV projection
    qkv_gemm<<<dim3(64, 48), 64, 0, stream>>>(xbf, wqb, wkb, wvb, qb, kb, vb);

    // 3. RoPE on Q, K
    rope_qk<<<8192, 256, 0, stream>>>(qb, kb, fcos, fsin);

    // 4. causal flash attention (MFMA)
    flash_attn_mfma<<<dim3(32, 32), 256, 0, stream>>>(qb, kb, vb, attnc);

    // 5. output projection
    out_gemm<<<dim3(64, 16), 64, 0, stream>>>(attnc, wob, out);
}

// Round 3
// 230.723 us; speedup vs baseline: 9.9670x; 1.3916x over previous
//
#include <hip/hip_runtime.h>
#include <hip/hip_bf16.h>
#include <cstdint>

typedef __attribute__((ext_vector_type(8))) short short8;
typedef __attribute__((ext_vector_type(4))) float f32x4;

#define B_  2
#define S_  2048
#define D_  1024
#define H_  16
#define HD  64

static __device__ __forceinline__ float bf2f(unsigned int u16) {
    union { unsigned int i; float f; } v; v.i = u16 << 16; return v.f;
}
static __device__ __forceinline__ unsigned short f2bf(float f) {
    union { float f; unsigned int i; } v; v.f = f;
    unsigned int r = v.i + 0x7FFFu + ((v.i >> 16) & 1u);
    return (unsigned short)(r >> 16);
}
// pack two floats to bf16x2 (hi in top 16, lo in bottom), round-half-up via +0x8000 then v_perm
static __device__ __forceinline__ unsigned pack_bf16(float hi, float lo) {
    union { float f; unsigned u; } h, l;
    h.f = hi; l.f = lo;
    return __builtin_amdgcn_perm(h.u + 0x8000u, l.u + 0x8000u, 0x07060302);
}
static __device__ __forceinline__ void load_lds_16B(const unsigned short* g, unsigned short* l) {
    __builtin_amdgcn_global_load_lds(
        (const __attribute__((address_space(1))) unsigned int*)g,
        (__attribute__((address_space(3))) unsigned int*)l, 16, 0, 0);
}

// ---------------- fp32 -> bf16 conversion ----------------
__global__ void cvt_f32_bf16(const float* __restrict__ src,
                             unsigned short* __restrict__ dst, int n4) {
    int i = blockIdx.x * 256 + threadIdx.x;
    if (i >= n4) return;
    float4 f = ((const float4*)src)[i];
    uint2 o;
    o.x = (unsigned int)f2bf(f.x) | ((unsigned int)f2bf(f.y) << 16);
    o.y = (unsigned int)f2bf(f.z) | ((unsigned int)f2bf(f.w) << 16);
    ((uint2*)dst)[i] = o;
}

// all 4 weights in one launch; dst regions contiguous (1M elems each)
__global__ void cvt_w4(const float* __restrict__ w0, const float* __restrict__ w1,
                       const float* __restrict__ w2, const float* __restrict__ w3,
                       unsigned short* __restrict__ dst) {
    int bid = blockIdx.x;                 // 0..4095
    int wsel = bid >> 10;
    const float* s = wsel == 0 ? w0 : wsel == 1 ? w1 : wsel == 2 ? w2 : w3;
    int i = (bid & 1023) * 256 + threadIdx.x;   // 0..262143
    float4 f = ((const float4*)s)[i];
    uint2 o;
    o.x = (unsigned int)f2bf(f.x) | ((unsigned int)f2bf(f.y) << 16);
    o.y = (unsigned int)f2bf(f.z) | ((unsigned int)f2bf(f.w) << 16);
    ((uint2*)dst)[(size_t)wsel * 262144 + i] = o;
}

// ---------------- fused QKV GEMM, m97-style 128x128 tile ----------------
// A: xbf [4096,1024] bf16. W (B^T): [1024,1024] bf16. BK=32, 4 waves 2x2.
__global__ __launch_bounds__(256) void qkv_gemm(
    const unsigned short* __restrict__ xbf,
    const unsigned short* __restrict__ wq,
    const unsigned short* __restrict__ wk,
    const unsigned short* __restrict__ wv,
    unsigned short* __restrict__ qb,
    unsigned short* __restrict__ kb,
    unsigned short* __restrict__ vb)
{
    __shared__ unsigned short As[128 * 32];
    __shared__ unsigned short Bs[128 * 32];

    const int tid  = threadIdx.x;
    const int w    = tid >> 6, lane = tid & 63;
    const int l15  = lane & 15, quad = lane >> 4;
    const int wrow = (w >> 1) * 64, wcol = (w & 1) * 64;

    const int m0 = blockIdx.x * 128;
    const int nc = blockIdx.y * 128;      // 0..3071, 128-aligned -> sel uniform
    const int sel = nc >> 10;
    const int n0 = nc & 1023;
    const unsigned short* __restrict__ W = sel == 0 ? wq : (sel == 1 ? wk : wv);
    unsigned short* __restrict__ Out = sel == 0 ? qb : (sel == 1 ? kb : vb);

    const int lr = lane >> 2, lc = (lane & 3) * 8;
    const unsigned short* ga = xbf + (size_t)(m0 + w * 16 + lr) * 1024 + lc;
    const unsigned short* gb = W   + (size_t)(n0 + w * 16 + lr) * 1024 + lc;
    unsigned short* la0 = As + (w * 16) * 32;          // wave-uniform bases
    unsigned short* la1 = As + (64 + w * 16) * 32;
    unsigned short* lb0 = Bs + (w * 16) * 32;
    unsigned short* lb1 = Bs + (64 + w * 16) * 32;

    f32x4 acc[4][4] = {};

    for (int k0 = 0; k0 < 1024; k0 += 32) {
        __syncthreads();
        load_lds_16B(ga + k0,             la0);
        load_lds_16B(ga + 64 * 1024 + k0, la1);
        load_lds_16B(gb + k0,             lb0);
        load_lds_16B(gb + 64 * 1024 + k0, lb1);
        __syncthreads();

        short8 a[4], b[4];
#pragma unroll
        for (int i = 0; i < 4; i++)
            a[i] = *(const short8*)&As[(wrow + i * 16 + l15) * 32 + quad * 8];
#pragma unroll
        for (int j = 0; j < 4; j++)
            b[j] = *(const short8*)&Bs[(wcol + j * 16 + l15) * 32 + quad * 8];
#pragma unroll
        for (int i = 0; i < 4; i++)
#pragma unroll
            for (int j = 0; j < 4; j++)
                acc[i][j] = __builtin_amdgcn_mfma_f32_16x16x32_bf16(a[i], b[j], acc[i][j], 0, 0, 0);
    }

    // epilogue: scatter to [B,H,S,hd] bf16
#pragma unroll
    for (int i = 0; i < 4; i++) {
#pragma unroll
        for (int r = 0; r < 4; r++) {
            int m = m0 + wrow + i * 16 + quad * 4 + r;
            int bb = m >> 11, s = m & 2047;
#pragma unroll
            for (int j = 0; j < 4; j++) {
                int n = n0 + wcol + j * 16 + l15;
                int h = n >> 6, d = n & 63;
                Out[(((size_t)(bb * H_ + h) * S_) + s) * HD + d] = f2bf(acc[i][j][r]);
            }
        }
    }
}

// ---------------- output GEMM, same structure, fp32 out ----------------
__global__ __launch_bounds__(256) void out_gemm(
    const unsigned short* __restrict__ A,
    const unsigned short* __restrict__ Bt,
    float* __restrict__ C)
{
    __shared__ unsigned short As[128 * 32];
    __shared__ unsigned short Bs[128 * 32];

    const int tid  = threadIdx.x;
    const int w    = tid >> 6, lane = tid & 63;
    const int l15  = lane & 15, quad = lane >> 4;
    const int wrow = (w >> 1) * 64, wcol = (w & 1) * 64;

    const int m0 = blockIdx.x * 128;
    const int n0 = blockIdx.y * 128;

    const int lr = lane >> 2, lc = (lane & 3) * 8;
    const unsigned short* ga = A  + (size_t)(m0 + w * 16 + lr) * 1024 + lc;
    const unsigned short* gb = Bt + (size_t)(n0 + w * 16 + lr) * 1024 + lc;
    unsigned short* la0 = As + (w * 16) * 32;
    unsigned short* la1 = As + (64 + w * 16) * 32;
    unsigned short* lb0 = Bs + (w * 16) * 32;
    unsigned short* lb1 = Bs + (64 + w * 16) * 32;

    f32x4 acc[4][4] = {};

    for (int k0 = 0; k0 < 1024; k0 += 32) {
        __syncthreads();
        load_lds_16B(ga + k0,             la0);
        load_lds_16B(ga + 64 * 1024 + k0, la1);
        load_lds_16B(gb + k0,             lb0);
        load_lds_16B(gb + 64 * 1024 + k0, lb1);
        __syncthreads();

        short8 a[4], b[4];
#pragma unroll
        for (int i = 0; i < 4; i++)
            a[i] = *(const short8*)&As[(wrow + i * 16 + l15) * 32 + quad * 8];
#pragma unroll
        for (int j = 0; j < 4; j++)
            b[j] = *(const short8*)&Bs[(wcol + j * 16 + l15) * 32 + quad * 8];
#pragma unroll
        for (int i = 0; i < 4; i++)
#pragma unroll
            for (int j = 0; j < 4; j++)
                acc[i][j] = __builtin_amdgcn_mfma_f32_16x16x32_bf16(a[i], b[j], acc[i][j], 0, 0, 0);
    }

#pragma unroll
    for (int i = 0; i < 4; i++)
#pragma unroll
        for (int r = 0; r < 4; r++) {
            int m = m0 + wrow + i * 16 + quad * 4 + r;
#pragma unroll
            for (int j = 0; j < 4; j++)
                C[(size_t)m * 1024 + n0 + wcol + j * 16 + l15] = acc[i][j][r];
        }
}

// ---------------- RoPE on Q and K in [B,H,S,hd] bf16 ---------------------
__global__ void rope_qk(unsigned short* __restrict__ qb,
                        unsigned short* __restrict__ kb,
                        const float* __restrict__ fcos,
                        const float* __restrict__ fsin)
{
    int idx = blockIdx.x * 256 + threadIdx.x;
    int t  = idx & 31;
    int s  = (idx >> 5) & (S_ - 1);
    int bh = idx >> 16;
    float c  = fcos[s * 32 + t];
    float si = fsin[s * 32 + t];
    size_t off = ((size_t)bh * S_ + s) * HD + 2 * t;

    unsigned int* qp = (unsigned int*)(qb + off);
    unsigned int u = *qp;
    float r = bf2f(u & 0xffffu), im = bf2f(u >> 16);
    *qp = pack_bf16(im * c + r * si, r * c - im * si);

    unsigned int* kp = (unsigned int*)(kb + off);
    u = *kp;
    r = bf2f(u & 0xffffu); im = bf2f(u >> 16);
    *kp = pack_bf16(im * c + r * si, r * c - im * si);
}

// ---------------- causal flash attention, MFMA ---------------------------
__global__ __launch_bounds__(256) void flash_attn_mfma(
    const unsigned short* __restrict__ qb,
    const unsigned short* __restrict__ kb,
    const unsigned short* __restrict__ vb,
    unsigned short* __restrict__ attnc)
{
    __shared__ unsigned short Ks[2][64][32];   // [khalf][j][kc] via global_load_lds
    __shared__ unsigned short Vt[64][72];      // V^T (row=d, col=j), +pad (reads 2-way)
    __shared__ unsigned short Pls[4][16][72];  // per-wave P round-trip

    const int bh   = blockIdx.x;
    const int qt   = blockIdx.y;
    const int b    = bh >> 4, h = bh & 15;
    const int tid  = threadIdx.x;
    const int w    = tid >> 6;
    const int lane = tid & 63;
    const int l15  = lane & 15;
    const int quad = lane >> 4;

    const size_t bhS = (size_t)bh * S_;

    short8 qfrag[2];
    {
        const unsigned short* qp = qb + (bhS + qt * 64 + w * 16 + l15) * HD + quad * 8;
        qfrag[0] = *(const short8*)(qp);
        qfrag[1] = *(const short8*)(qp + 32);
    }

    // staging address pieces
    const int klr = lane >> 2, klc = (lane & 3) * 8;        // K via global_load_lds
    const int vdg = tid >> 5, vp = tid & 31;                // V transpose mapping

    f32x4 O[4] = {};
    float mrow = -INFINITY;
    float lrow = 0.0f;
    const float sc = 0.125f * 1.44269504f;

    for (int jt = 0; jt <= qt; jt++) {
        const int j0 = jt * 64;
        // ---- K tile: direct-to-LDS, layout [kh][row][32] ----
        {
            const unsigned short* kg = kb + (bhS + j0 + w * 16 + klr) * HD + klc;
            load_lds_16B(kg,      &Ks[0][w * 16][0]);
            load_lds_16B(kg + 32, &Ks[1][w * 16][0]);
        }
        // ---- V^T tile: perm-packed transpose ----
        {
            const unsigned short* vptr = vb + (bhS + j0 + 2 * vp) * HD + vdg * 8;
            uint4 v0 = *(const uint4*)vptr;
            uint4 v1 = *(const uint4*)(vptr + HD);
            const unsigned* a0 = (const unsigned*)&v0;
            const unsigned* a1 = (const unsigned*)&v1;
#pragma unroll
            for (int c = 0; c < 4; c++) {
                *(unsigned*)&Vt[vdg * 8 + 2 * c][2 * vp] =
                    __builtin_amdgcn_perm(a1[c], a0[c], 0x05040100);
                *(unsigned*)&Vt[vdg * 8 + 2 * c + 1][2 * vp] =
                    __builtin_amdgcn_perm(a1[c], a0[c], 0x07060302);
            }
        }
        __syncthreads();

        const bool diag  = (jt == qt);
        const int  nsub  = diag ? (w + 1) : 4;
        const int  kgmax = (nsub + 1) >> 1;

        // ---- S^T = K·Q^T ----
        f32x4 Sacc[4];
        float tmax = -INFINITY;
        for (int sub = 0; sub < nsub; sub++) {
            f32x4 s = {};
#pragma unroll
            for (int kh = 0; kh < 2; kh++) {
                short8 kf = *(const short8*)&Ks[kh][sub * 16 + l15][quad * 8];
                s = __builtin_amdgcn_mfma_f32_16x16x32_bf16(kf, qfrag[kh], s, 0, 0, 0);
            }
#pragma unroll
            for (int r = 0; r < 4; r++) {
                float v = s[r] * sc;
                if (diag && (sub * 16 + quad * 4 + r > w * 16 + l15)) v = -INFINITY;
                s[r] = v;
                tmax = fmaxf(tmax, v);
            }
            Sacc[sub] = s;
        }
        tmax = fmaxf(tmax, __shfl_xor(tmax, 16, 64));
        tmax = fmaxf(tmax, __shfl_xor(tmax, 32, 64));

        float mnew = fmaxf(mrow, tmax);
        float ccr  = __builtin_amdgcn_exp2f(mrow - mnew);

        float psum = 0.0f;
        for (int sub = 0; sub < nsub; sub++) {
            f32x4 s = Sacc[sub];
            float p0 = __builtin_amdgcn_exp2f(s[0] - mnew);
            float p1 = __builtin_amdgcn_exp2f(s[1] - mnew);
            float p2 = __builtin_amdgcn_exp2f(s[2] - mnew);
            float p3 = __builtin_amdgcn_exp2f(s[3] - mnew);
            psum += (p0 + p1) + (p2 + p3);
            uint2 pk;
            pk.x = pack_bf16(p1, p0);
            pk.y = pack_bf16(p3, p2);
            *(uint2*)&Pls[w][l15][sub * 16 + quad * 4] = pk;
        }
        if (diag) {
            for (int sub = nsub; sub < 2 * kgmax; sub++) {
                uint2 z; z.x = 0u; z.y = 0u;
                *(uint2*)&Pls[w][l15][sub * 16 + quad * 4] = z;
            }
        }
        psum += __shfl_xor(psum, 16, 64);
        psum += __shfl_xor(psum, 32, 64);
        lrow = lrow * ccr + psum;
        mrow = mnew;

#pragma unroll
        for (int r = 0; r < 4; r++) {
            float ccq = __shfl(ccr, quad * 4 + r, 64);
#pragma unroll
            for (int dt = 0; dt < 4; dt++) O[dt][r] *= ccq;
        }

        for (int kg = 0; kg < kgmax; kg++) {
            short8 pf = *(const short8*)&Pls[w][l15][kg * 32 + quad * 8];
#pragma unroll
            for (int dt = 0; dt < 4; dt++) {
                short8 vf = *(const short8*)&Vt[dt * 16 + l15][kg * 32 + quad * 8];
                O[dt] = __builtin_amdgcn_mfma_f32_16x16x32_bf16(pf, vf, O[dt], 0, 0, 0);
            }
        }
        __syncthreads();
    }

    float inv = 1.0f / lrow;
#pragma unroll
    for (int r = 0; r < 4; r++) {
        float invq = __shfl(inv, quad * 4 + r, 64);
        int qabs = qt * 64 + w * 16 + quad * 4 + r;
        unsigned short* op = attnc + (((size_t)b * S_ + qabs) * H_ + h) * HD + l15;
#pragma unroll
        for (int dt = 0; dt < 4; dt++)
            op[dt * 16] = f2bf(O[dt][r] * invq);
    }
}

// ---------------- launch ----------------
extern "C" void kernel_launch(void* const* d_in, const int* in_sizes, int n_in,
                              void* d_out, int out_size, void* d_ws, size_t ws_size,
                              hipStream_t stream) {
    const float* x    = (const float*)d_in[0];
    const float* fcos = (const float*)d_in[1];
    const float* fsin = (const float*)d_in[2];
    const float* Wq   = (const float*)d_in[3];
    const float* Wk   = (const float*)d_in[4];
    const float* Wv   = (const float*)d_in[5];
    const float* Wo   = (const float*)d_in[6];
    float* out = (float*)d_out;

    unsigned short* ws = (unsigned short*)d_ws;
    unsigned short* xbf = ws;                      // 4M elems
    unsigned short* wqb = xbf + 4096 * 1024;       // 1M each, contiguous
    unsigned short* wkb = wqb + 1024 * 1024;
    unsigned short* wvb = wkb + 1024 * 1024;
    unsigned short* wob = wvb + 1024 * 1024;
    unsigned short* qb  = wob + 1024 * 1024;
    unsigned short* kb  = qb + 4096 * 1024;
    unsigned short* vb  = kb + 4096 * 1024;
    unsigned short* attnc = vb + 4096 * 1024;

    cvt_f32_bf16<<<4096, 256, 0, stream>>>(x, xbf, 4096 * 1024 / 4);
    cvt_w4<<<4096, 256, 0, stream>>>(Wq, Wk, Wv, Wo, wqb);

    qkv_gemm<<<dim3(32, 24), 256, 0, stream>>>(xbf, wqb, wkb, wvb, qb, kb, vb);

    rope_qk<<<8192, 256, 0, stream>>>(qb, kb, fcos, fsin);

    flash_attn_mfma<<<dim3(32, 32), 256, 0, stream>>>(qb, kb, vb, attnc);

    out_gemm<<<dim3(32, 8), 256, 0, stream>>>(attnc, wob, out);
}